// Round 13
// baseline (61.560 us; speedup 1.0000x reference)
//
#include <hip/hip_runtime.h>
#include <hip/hip_bf16.h>

#define NS 2048
#define ND 64

typedef __attribute__((ext_vector_type(8))) short short8;
typedef __attribute__((ext_vector_type(4))) short short4v;
typedef __attribute__((ext_vector_type(4))) float f32x4;

static __device__ __forceinline__ short f2bf(float f) {
    union { __hip_bfloat16 h; short s; } u;
    u.h = __float2bfloat16(f);
    return u.s;
}
static __device__ __forceinline__ unsigned int pack2(float lo, float hi) {
    return (unsigned int)(unsigned short)f2bf(lo) |
           ((unsigned int)(unsigned short)f2bf(hi) << 16);
}
static __device__ __forceinline__ float exp2_fast(float x) {
    float r;
    asm("v_exp_f32 %0, %1" : "=v"(r) : "v"(x));
    return r;
}
static __device__ __forceinline__ unsigned int cvt_pk_bf16(float lo, float hi) {
    unsigned int w;
    asm("v_cvt_pk_bf16_f32 %0, %1, %2" : "=v"(w) : "v"(lo), "v"(hi));
    return w;
}

// ---------------- detect mask element stride (fallback path only) ----------
__global__ void detect_mask_kernel(const unsigned char* __restrict__ mask,
                                   int* __restrict__ flag) {
    const int i = threadIdx.x;  // 64 threads x 64 bytes
    unsigned int acc = 0;
    const uchar4* p = (const uchar4*)(mask + i * 64);
    #pragma unroll
    for (int j = 0; j < 16; ++j) {
        uchar4 v = p[j];
        acc |= (unsigned int)v.y | v.z | v.w;  // bytes at (off%4)!=0
    }
    const unsigned long long any = __ballot(acc != 0);
    if (i == 0) *flag = (any == 0ULL) ? 4 : 1;
}

// ---------------- pre-pass: K/V tile images + mask bit-words ---------------
// (round-11/12 proven; FROZEN)  IMG per (bh,t): 8KB = [K 4x1KB | V 4x1KB];
// 16B slot at chunk*1024 + lane*16 holds that lane's full MFMA A-fragment.
// Mask bits (causal pre-folded). Mask-stride detection done inline per block
// (scan of M[0..4095]) — no separate detect launch on the main path.
__global__ void prep_all(const float* __restrict__ K,
                         const float* __restrict__ V,
                         const unsigned char* __restrict__ M,
                         unsigned char* __restrict__ IMG,
                         unsigned int* __restrict__ Mbits) {
    if (blockIdx.x < 2048) {
        const int bid = blockIdx.x;          // (bh, T)
        const int bh = bid >> 6, T = bid & 63;
        const int i = threadIdx.x;
        __shared__ __align__(16) unsigned char img[8192];

        const int row = i >> 3;              // 0..31
        const int d0  = (i & 7) * 8;

        // ---- K ----
        {
            const float* src = K + ((size_t)(bh * NS + T * 32 + row)) * ND + d0;
            float4 f0 = ((const float4*)src)[0];
            float4 f1 = ((const float4*)src)[1];
            const float f[8] = {f0.x, f0.y, f0.z, f0.w, f1.x, f1.y, f1.z, f1.w};
            const int n = row >> 4, cc = row & 15;
            #pragma unroll
            for (int jp = 0; jp < 4; ++jp) {
                const int d  = d0 + 2 * jp;
                const int ch = d >> 5, dd = d & 31;
                const int g  = (dd & 15) >> 2;
                const int jj = (dd >> 4) * 2 + ((dd >> 1) & 1);
                *(unsigned int*)(img + (n * 2 + ch) * 1024 + (g * 16 + cc) * 16 + jj * 4) =
                    pack2(f[2 * jp], f[2 * jp + 1]);
            }
        }
        // ---- V ----
        {
            const int kv = row;
            const float* src = V + ((size_t)(bh * NS + T * 32 + kv)) * ND + d0;
            float4 f0 = ((const float4*)src)[0];
            float4 f1 = ((const float4*)src)[1];
            const float f[8] = {f0.x, f0.y, f0.z, f0.w, f1.x, f1.y, f1.z, f1.w};
            const int kl  = kv & ~1;
            const int q15 = kl & 15;
            const int g   = q15 >> 2;
            const int jj  = (kl >> 4) * 2 + ((q15 >> 1) & 1);
            const int half = (kv & 1) * 2;
            #pragma unroll
            for (int e = 0; e < 8; ++e) {
                const int d  = d0 + e;
                const int n4 = d >> 4, cv = d & 15;
                *(short*)(img + 4096 + n4 * 1024 + (g * 16 + cv) * 16 + jj * 4 + half) =
                    f2bf(f[e]);
            }
        }
        __syncthreads();
        uint4* dst = (uint4*)(IMG + ((size_t)bid << 13));
        const uint4* srcl = (const uint4*)img;
        dst[i * 2]     = srcl[i * 2];
        dst[i * 2 + 1] = srcl[i * 2 + 1];
    } else {
        // ---- inline mask-stride detection (first 4096 bytes of M) ----
        __shared__ int msh;
        {
            unsigned int accv = 0;
            if (threadIdx.x < 64) {
                const uint4* p4 = (const uint4*)(M + threadIdx.x * 64);
                #pragma unroll
                for (int jj = 0; jj < 4; ++jj) {
                    uint4 v = p4[jj];
                    accv |= (v.x & 0xFFFFFF00u) | (v.y & 0xFFFFFF00u) |
                            (v.z & 0xFFFFFF00u) | (v.w & 0xFFFFFF00u);
                }
            }
            const unsigned long long any = __ballot(accv != 0);
            if (threadIdx.x == 0) msh = (any == 0ULL) ? 4 : 1;
        }
        __syncthreads();
        const int ms = msh;

        const int id3 = (blockIdx.x - 2048) * 256 + threadIdx.x;   // 262144
        const int tt = id3 & 63, q = (id3 >> 6) & 2047, b = id3 >> 17;
        unsigned int w = 0;
        if (ms == 1) {
            const uint4* p = (const uint4*)(M + ((size_t)(b * NS + q)) * NS + tt * 32);
            uint4 A = p[0], B = p[1];
            const unsigned int u[8] = {A.x, A.y, A.z, A.w, B.x, B.y, B.z, B.w};
            #pragma unroll
            for (int i = 0; i < 8; ++i) {
                const unsigned int nib = (((u[i] & 0x01010101u) * 0x01020408u) >> 24) & 0xFu;
                w |= nib << (4 * i);
            }
        } else {
            const uint4* p = (const uint4*)(M + (((size_t)(b * NS + q)) * NS) * 4 + tt * 128);
            #pragma unroll
            for (int i = 0; i < 8; ++i) {
                uint4 A = p[i];
                w |= ((A.x & 1u) << (4 * i)) | ((A.y & 1u) << (4 * i + 1)) |
                     ((A.z & 1u) << (4 * i + 2)) | ((A.w & 1u) << (4 * i + 3));
            }
        }
        // causal fold: clear bits with kv = 32*tt + j > q
        const int qrel = q - 32 * tt;
        if (qrel < 0) w = 0;
        else if (qrel < 31) w &= ((2u << qrel) - 1u);
        Mbits[((size_t)(b * 64 + (q >> 5)) * 64 + tt) * 32 + (q & 31)] = w;
    }
}

// ---------------- main attention kernel ----------------
// Barrier-free main loop: each wave (p = wid&1, s = wid>>1) independently
// walks its parity tiles t = p, p+2, ... <= 2qi+s, loading MFMA fragments
// DIRECTLY global->VGPR from the per-lane-contiguous IMG (8 coalesced
// dwordx4 per tile, L2-resident), register ping-pong prefetch one tile
// ahead. No LDS staging, no syncthreads, no waitcnt in the loop. Fixed-base
// softmax + ones-row MFMA l-sum as before; parity partials merge through
// LDS with a single barrier at the end.
__launch_bounds__(256)
__global__ void attn_main(const float* __restrict__ Q,
                          const unsigned char* __restrict__ IMG,
                          const unsigned int* __restrict__ Mbits,
                          float* __restrict__ O) {
    const int idx = blockIdx.x;
    const int j   = (idx & 511) >> 5;
    const int bh  = idx & 31;
    const int qi  = (idx < 512) ? (31 - j) : j;   // 64-row q-tile, CU-balanced
    const int b   = bh >> 4;

    const int tid  = threadIdx.x;
    const int wid  = tid >> 6;
    const int lane = tid & 63;
    const int g = lane >> 4;
    const int c = lane & 15;
    const int p = wid & 1;     // kv-tile parity this wave computes
    const int s = wid >> 1;    // q 32-row subset

    const int q0w = qi * 64 + s * 32;

    const size_t bhoff = (size_t)bh * NS * ND;
    const float* Qb = Q + bhoff;
    float*       Ob = O + bhoff;
    const unsigned char* Tb = IMG + ((size_t)bh << 19);   // 64 tiles * 8192
    const unsigned int*  Mw = Mbits + ((size_t)(b * 64 + 2 * qi + s) << 11);

    __shared__ __align__(16) float MB[5120];   // 20KB, merge only

    // Q fragments (2 m-tiles) with 0.125*log2(e) folded in
    const float QS = 0.18033688f;
    short8 aq[2][2];
    #pragma unroll
    for (int m = 0; m < 2; ++m) {
        const float* qrow = Qb + (size_t)(q0w + m * 16 + c) * ND;
        #pragma unroll
        for (int ch = 0; ch < 2; ++ch) {
            float4 x0 = *reinterpret_cast<const float4*>(qrow + ch * 32 + g * 4);
            float4 x1 = *reinterpret_cast<const float4*>(qrow + ch * 32 + 16 + g * 4);
            short8 fr;
            fr[0]=f2bf(x0.x*QS); fr[1]=f2bf(x0.y*QS); fr[2]=f2bf(x0.z*QS); fr[3]=f2bf(x0.w*QS);
            fr[4]=f2bf(x1.x*QS); fr[5]=f2bf(x1.y*QS); fr[6]=f2bf(x1.z*QS); fr[7]=f2bf(x1.w*QS);
            aq[m][ch] = fr;
        }
    }

    // ones-row A fragment: row 0 = 1.0 (lanes with c==0), else 0
    const short ov = (c == 0) ? (short)0x3F80 : (short)0;
    short8 onesf;
    #pragma unroll
    for (int e = 0; e < 8; ++e) onesf[e] = ov;

    f32x4 acc[2][4];
    f32x4 acc_l[2];
    #pragma unroll
    for (int m = 0; m < 2; ++m) {
        acc_l[m] = (f32x4){0.f, 0.f, 0.f, 0.f};
        #pragma unroll
        for (int n4 = 0; n4 < 4; ++n4) acc[m][n4] = (f32x4){0.f, 0.f, 0.f, 0.f};
    }

    const int tmax = 2 * qi + s;    // last tile whose rows this wave needs

    // direct global->VGPR fragment load for tile T (8x global_load_dwordx4)
#define LOADT(T, KF, AV, MK0, MK1) do { \
    const short8* tp_ = (const short8*)(Tb + ((size_t)(T) << 13) + (lane << 4)); \
    KF[0] = tp_[0];   KF[1] = tp_[64];  KF[2] = tp_[128]; KF[3] = tp_[192]; \
    AV[0] = tp_[256]; AV[1] = tp_[320]; AV[2] = tp_[384]; AV[3] = tp_[448]; \
    MK0 = Mw[(T) * 32 + c]; \
    MK1 = Mw[(T) * 32 + 16 + c]; \
} while (0)

#define COMPUTE(KF, AV, MK0, MK1) do { \
    _Pragma("unroll") \
    for (int m = 0; m < 2; ++m) { \
        f32x4 s0 = (f32x4){0.f, 0.f, 0.f, 0.f}; \
        f32x4 s1 = (f32x4){0.f, 0.f, 0.f, 0.f}; \
        s0 = __builtin_amdgcn_mfma_f32_16x16x32_bf16(KF[0], aq[m][0], s0, 0, 0, 0); \
        s0 = __builtin_amdgcn_mfma_f32_16x16x32_bf16(KF[1], aq[m][1], s0, 0, 0, 0); \
        s1 = __builtin_amdgcn_mfma_f32_16x16x32_bf16(KF[2], aq[m][0], s1, 0, 0, 0); \
        s1 = __builtin_amdgcn_mfma_f32_16x16x32_bf16(KF[3], aq[m][1], s1, 0, 0, 0); \
        const unsigned int mk = m ? (MK1) : (MK0); \
        float pv[8]; \
        _Pragma("unroll") \
        for (int r = 0; r < 4; ++r) { \
            const unsigned int b0 = (mk >> (4 * g + r)) & 1u; \
            const unsigned int b1 = (mk >> (16 + 4 * g + r)) & 1u; \
            pv[r]     = exp2_fast(b0 ? s0[r] : -INFINITY); \
            pv[4 + r] = exp2_fast(b1 ? s1[r] : -INFINITY); \
        } \
        union { unsigned int u[4]; short8 v; } pfu_; \
        pfu_.u[0] = cvt_pk_bf16(pv[0], pv[1]); \
        pfu_.u[1] = cvt_pk_bf16(pv[2], pv[3]); \
        pfu_.u[2] = cvt_pk_bf16(pv[4], pv[5]); \
        pfu_.u[3] = cvt_pk_bf16(pv[6], pv[7]); \
        const short8 pf = pfu_.v; \
        _Pragma("unroll") \
        for (int n4 = 0; n4 < 4; ++n4) \
            acc[m][n4] = __builtin_amdgcn_mfma_f32_16x16x32_bf16(AV[n4], pf, acc[m][n4], 0, 0, 0); \
        acc_l[m] = __builtin_amdgcn_mfma_f32_16x16x32_bf16(onesf, pf, acc_l[m], 0, 0, 0); \
    } \
} while (0)

    // register ping-pong: prefetch one tile (t+2) ahead, zero sync ops
    {
        short8 kfA[4], avA[4], kfB[4], avB[4];
        unsigned int a0 = 0, a1 = 0, b0m = 0, b1m = 0;
        int t = p;
        if (t <= tmax) {
            LOADT(t, kfA, avA, a0, a1);
            for (;;) {
                const int tn = t + 2;
                if (tn <= tmax) LOADT(tn, kfB, avB, b0m, b1m);
                COMPUTE(kfA, avA, a0, a1);
                t = tn;
                if (t > tmax) break;
                const int tn2 = t + 2;
                if (tn2 <= tmax) LOADT(tn2, kfA, avA, a0, a1);
                COMPUTE(kfB, avB, b0m, b1m);
                t = tn2;
                if (t > tmax) break;
            }
        }
    }

    // ---- merge parity partials (pure addition; fixed base) ----
    if (p == 1) {
        #pragma unroll
        for (int m = 0; m < 2; ++m) {
            #pragma unroll
            for (int n4 = 0; n4 < 4; ++n4)
                *(f32x4*)&MB[(((s * 2 + m) * 4 + n4) * 64 + lane) * 4] = acc[m][n4];
            *(f32x4*)&MB[4096 + ((s * 2 + m) * 64 + lane) * 4] = acc_l[m];
        }
    }
    __syncthreads();
    if (p == 0) {
        #pragma unroll
        for (int m = 0; m < 2; ++m) {
            #pragma unroll
            for (int n4 = 0; n4 < 4; ++n4) {
                f32x4 o = *(const f32x4*)&MB[(((s * 2 + m) * 4 + n4) * 64 + lane) * 4];
                acc[m][n4][0] += o[0]; acc[m][n4][1] += o[1];
                acc[m][n4][2] += o[2]; acc[m][n4][3] += o[3];
            }
            f32x4 ol = *(const f32x4*)&MB[4096 + ((s * 2 + m) * 64 + lane) * 4];
            acc_l[m][0] += ol[0];
        }
        #pragma unroll
        for (int m = 0; m < 2; ++m) {
            const int q = q0w + m * 16 + c;
            const float lsum = __shfl(acc_l[m][0], c);   // row sum at lane c, reg 0
            const float inv = (lsum > 0.f) ? (1.f / lsum) : 0.f;
            float* orow = Ob + (size_t)q * ND;
            #pragma unroll
            for (int n4 = 0; n4 < 4; ++n4) {
                float4 o;
                o.x = acc[m][n4][0] * inv;
                o.y = acc[m][n4][1] * inv;
                o.z = acc[m][n4][2] * inv;
                o.w = acc[m][n4][3] * inv;
                *(float4*)(orow + n4 * 16 + 4 * g) = o;
            }
        }
    }
#undef LOADT
#undef COMPUTE
}

// ---------------- fallback (round-2 kernel, no workspace images) -----------
__launch_bounds__(128, 2)
__global__ void attn_fwd_fb(const float* __restrict__ Q,
                            const float* __restrict__ K,
                            const float* __restrict__ V,
                            const unsigned char* __restrict__ M,
                            float* __restrict__ O,
                            const int* __restrict__ mstride_p) {
    const int ms  = *mstride_p;
    const int idx = blockIdx.x;
    const int qi  = 31 - (idx >> 5);
    const int bh  = idx & 31;
    const int b   = bh >> 4;

    const int tid  = threadIdx.x;
    const int wid  = tid >> 6;
    const int lane = tid & 63;
    const int g = lane >> 4;
    const int c = lane & 15;

    const int q0w = qi * 64 + wid * 32;

    const size_t bhoff = (size_t)bh * NS * ND;
    const float* Qb = Q + bhoff;
    const float* Kb = K + bhoff;
    const float* Vb = V + bhoff;
    float*       Ob = O + bhoff;
    const unsigned char* Mb = M + (size_t)b * NS * NS * (size_t)ms;

    __shared__ __align__(16) unsigned char smem[2][8192];

    short8 aq[2][2];
    #pragma unroll
    for (int m = 0; m < 2; ++m) {
        const float* qrow = Qb + (size_t)(q0w + m * 16 + c) * ND;
        #pragma unroll
        for (int ch = 0; ch < 2; ++ch) {
            float4 x0 = *reinterpret_cast<const float4*>(qrow + ch * 32 + g * 4);
            float4 x1 = *reinterpret_cast<const float4*>(qrow + ch * 32 + 16 + g * 4);
            short8 fr;
            fr[0]=f2bf(x0.x); fr[1]=f2bf(x0.y); fr[2]=f2bf(x0.z); fr[3]=f2bf(x0.w);
            fr[4]=f2bf(x1.x); fr[5]=f2bf(x1.y); fr[6]=f2bf(x1.z); fr[7]=f2bf(x1.w);
            aq[m][ch] = fr;
        }
    }

    f32x4 acc[2][4];
    float m_run[2], l_run[2];
    #pragma unroll
    for (int m = 0; m < 2; ++m) {
        m_run[m] = -INFINITY; l_run[m] = 0.f;
        #pragma unroll
        for (int n4 = 0; n4 < 4; ++n4) acc[m][n4] = (f32x4){0.f, 0.f, 0.f, 0.f};
    }

    const int NT = 2 * qi + 2;

    const int krow = tid >> 2;
    const int kcb  = (tid & 3) * 16;
    const int ksw  = (krow & 7) << 4;
    const int vkp  = tid >> 3;
    const int vdb  = tid & 7;
    const int vg   = (vkp >> 1) & 3;
    const int vep  = (vkp & 1) + 2 * (vkp >> 3);
    const float* kbase = Kb + (size_t)krow * ND + kcb;
    const float* vbase = Vb + (size_t)(2 * vkp) * ND + vdb * 8;

    float4 kin0, kin1, kin2, kin3, vin0, vin1, vin2, vin3;

#define STAGE_LOAD(T) do { \
    const float* kp_ = kbase + (size_t)(T) * 32 * ND; \
    kin0 = *(const float4*)(kp_);      kin1 = *(const float4*)(kp_ + 4); \
    kin2 = *(const float4*)(kp_ + 8);  kin3 = *(const float4*)(kp_ + 12); \
    const float* vp_ = vbase + (size_t)(T) * 32 * ND; \
    vin0 = *(const float4*)(vp_);      vin1 = *(const float4*)(vp_ + 4); \
    vin2 = *(const float4*)(vp_ + ND); vin3 = *(const float4*)(vp_ + ND + 4); \
} while (0)

#define STAGE_WRITE(BUF) do { \
    unsigned char* kb_ = smem[BUF]; \
    short8 w0, w1; \
    w0[0]=f2bf(kin0.x); w0[1]=f2bf(kin0.y); w0[2]=f2bf(kin0.z); w0[3]=f2bf(kin0.w); \
    w0[4]=f2bf(kin1.x); w0[5]=f2bf(kin1.y); w0[6]=f2bf(kin1.z); w0[7]=f2bf(kin1.w); \
    w1[0]=f2bf(kin2.x); w1[1]=f2bf(kin2.y); w1[2]=f2bf(kin2.z); w1[3]=f2bf(kin2.w); \
    w1[4]=f2bf(kin3.x); w1[5]=f2bf(kin3.y); w1[6]=f2bf(kin3.z); w1[7]=f2bf(kin3.w); \
    *(short8*)(kb_ + krow * 128 + ((kcb * 2) ^ ksw))      = w0; \
    *(short8*)(kb_ + krow * 128 + ((kcb * 2 + 16) ^ ksw)) = w1; \
    unsigned char* vb_ = smem[BUF] + 4096; \
    const float lo_[8] = {vin0.x, vin0.y, vin0.z, vin0.w, vin1.x, vin1.y, vin1.z, vin1.w}; \
    const float hi_[8] = {vin2.x, vin2.y, vin2.z, vin2.w, vin3.x, vin3.y, vin3.z, vin3.w}; \
    _Pragma("unroll") \
    for (int j_ = 0; j_ < 8; ++j_) { \
        const int d_ = vdb * 8 + j_; \
        const int n4_ = d_ >> 4; \
        const int cc_ = d_ & 15; \
        const int aw_ = ((n4_ * 4 + vep) * 64 + ((vg * 16 + cc_) ^ ((vep << 3) | n4_))) * 4; \
        *(unsigned int*)(vb_ + aw_) = pack2(lo_[j_], hi_[j_]); \
    } \
} while (0)

    STAGE_LOAD(0);
    STAGE_WRITE(0);
    __syncthreads();

    const float SC = 0.125f;

    for (int t = 0; t < NT; ++t) {
        const int cur = t & 1;
        const bool havenext = (t + 1 < NT);
        if (havenext) STAGE_LOAD(t + 1);

        const unsigned char* kb = smem[cur];
        const int sw = (c & 7) << 4;
        short8 kf[2][2];
        #pragma unroll
        for (int n = 0; n < 2; ++n) {
            const int row = n * 16 + c;
            #pragma unroll
            for (int ch = 0; ch < 2; ++ch) {
                short4v lo = *(const short4v*)(kb + row * 128 + ((ch * 64 + g * 8) ^ sw));
                short4v hi = *(const short4v*)(kb + row * 128 + ((ch * 64 + g * 8 + 32) ^ sw));
                short8 fr;
                fr[0]=lo[0]; fr[1]=lo[1]; fr[2]=lo[2]; fr[3]=lo[3];
                fr[4]=hi[0]; fr[5]=hi[1]; fr[6]=hi[2]; fr[7]=hi[3];
                kf[n][ch] = fr;
            }
        }
        const unsigned char* vbuf = smem[cur] + 4096;
        short8 av[4];
        #pragma unroll
        for (int n4 = 0; n4 < 4; ++n4) {
            short8 fr;
            #pragma unroll
            for (int ep = 0; ep < 4; ++ep) {
                unsigned int w = *(const unsigned int*)
                    (vbuf + (((n4 * 4 + ep) * 64 + (lane ^ ((ep << 3) | n4))) * 4));
                fr[2 * ep]     = (short)(w & 0xffff);
                fr[2 * ep + 1] = (short)(w >> 16);
            }
            av[n4] = fr;
        }

        const int kv0 = t * 32;
        #pragma unroll
        for (int m = 0; m < 2; ++m) {
            const int q = q0w + m * 16 + c;

            f32x4 s[2];
            #pragma unroll
            for (int n = 0; n < 2; ++n) {
                f32x4 z = {0.f, 0.f, 0.f, 0.f};
                z = __builtin_amdgcn_mfma_f32_16x16x32_bf16(kf[n][0], aq[m][0], z, 0, 0, 0);
                z = __builtin_amdgcn_mfma_f32_16x16x32_bf16(kf[n][1], aq[m][1], z, 0, 0, 0);
                s[n] = z;
            }

            unsigned int mk0, mk1;
            if (ms == 1) {
                mk0 = *(const unsigned int*)(Mb + (size_t)q * NS + kv0 + 4 * g);
                mk1 = *(const unsigned int*)(Mb + (size_t)q * NS + kv0 + 16 + 4 * g);
            } else {
                const uint4 a4 = *(const uint4*)(Mb + ((size_t)q * NS + kv0 + 4 * g) * 4);
                const uint4 b4 = *(const uint4*)(Mb + ((size_t)q * NS + kv0 + 16 + 4 * g) * 4);
                mk0 = (a4.x?1u:0u) | (a4.y?0x100u:0u) | (a4.z?0x10000u:0u) | (a4.w?0x1000000u:0u);
                mk1 = (b4.x?1u:0u) | (b4.y?0x100u:0u) | (b4.z?0x10000u:0u) | (b4.w?0x1000000u:0u);
            }

            float mx = -INFINITY;
            #pragma unroll
            for (int n = 0; n < 2; ++n) {
                const unsigned int mk = n ? mk1 : mk0;
                #pragma unroll
                for (int r = 0; r < 4; ++r) {
                    const int kv = kv0 + n * 16 + 4 * g + r;
                    const bool keep = (((mk >> (8 * r)) & 0xffu) != 0u) && (kv <= q);
                    const float val = keep ? s[n][r] * SC : -INFINITY;
                    s[n][r] = val;
                    mx = fmaxf(mx, val);
                }
            }
            mx = fmaxf(mx, __shfl_xor(mx, 16));
            mx = fmaxf(mx, __shfl_xor(mx, 32));

            const float m_new = fmaxf(m_run[m], mx);
            const float alpha = (m_run[m] == -INFINITY) ? 0.f : __expf(m_run[m] - m_new);
            m_run[m] = m_new;
            const float msafe = (m_new == -INFINITY) ? 0.f : m_new;

            float sum = 0.f;
            short8 pf;
            #pragma unroll
            for (int n = 0; n < 2; ++n)
                #pragma unroll
                for (int r = 0; r < 4; ++r) {
                    const float pvv = __expf(s[n][r] - msafe);
                    sum += pvv;
                    pf[n * 4 + r] = f2bf(pvv);
                }
            sum += __shfl_xor(sum, 16);
            sum += __shfl_xor(sum, 32);
            l_run[m] = l_run[m] * alpha + sum;

            #pragma unroll
            for (int n4 = 0; n4 < 4; ++n4) {
                f32x4 o = acc[m][n4];
                o[0] *= alpha; o[1] *= alpha; o[2] *= alpha; o[3] *= alpha;
                o = __builtin_amdgcn_mfma_f32_16x16x32_bf16(av[n4], pf, o, 0, 0, 0);
                acc[m][n4] = o;
            }
        }

        if (havenext) STAGE_WRITE(cur ^ 1);
        __syncthreads();
    }

    #pragma unroll
    for (int m = 0; m < 2; ++m) {
        const int q = q0w + m * 16 + c;
        const float inv = (l_run[m] > 0.f) ? (1.f / l_run[m]) : 0.f;
        float* orow = Ob + (size_t)q * ND;
        #pragma unroll
        for (int n4 = 0; n4 < 4; ++n4) {
            float4 o;
            o.x = acc[m][n4][0] * inv;
            o.y = acc[m][n4][1] * inv;
            o.z = acc[m][n4][2] * inv;
            o.w = acc[m][n4][3] * inv;
            *(float4*)(orow + n4 * 16 + 4 * g) = o;
        }
    }
#undef STAGE_LOAD
#undef STAGE_WRITE
}

extern "C" void kernel_launch(void* const* d_in, const int* in_sizes, int n_in,
                              void* d_out, int out_size, void* d_ws, size_t ws_size,
                              hipStream_t stream) {
    const float* Q = (const float*)d_in[0];
    const float* K = (const float*)d_in[1];
    const float* V = (const float*)d_in[2];
    const unsigned char* M = (const unsigned char*)d_in[3];
    float* O = (float*)d_out;

    unsigned char* ws = (unsigned char*)d_ws;
    const size_t IMG_SZ  = (size_t)2048 * 8192;              // 16 MB
    const size_t BITS_SZ = (size_t)2 * 64 * 64 * 32 * 4;     // 2 MB
    const size_t NEED = 1024 + IMG_SZ + BITS_SZ;

    if (ws_size >= NEED) {
        unsigned char* IMG  = ws + 1024;
        unsigned int* Mbits = (unsigned int*)(ws + 1024 + IMG_SZ);
        hipLaunchKernelGGL(prep_all, dim3(3072), dim3(256), 0, stream,
                           K, V, M, IMG, Mbits);
        hipLaunchKernelGGL(attn_main, dim3(1024), dim3(256), 0, stream,
                           Q, IMG, Mbits, O);
    } else {
        int* flag = (int*)ws;
        hipLaunchKernelGGL(detect_mask_kernel, dim3(1), dim3(64), 0, stream, M, flag);
        hipLaunchKernelGGL(attn_fwd_fb, dim3(1024), dim3(128), 0, stream,
                           Q, K, V, M, O, flag);
    }
}

// Round 14
// 50.630 us; speedup vs baseline: 1.2159x; 1.2159x over previous
//
#include <hip/hip_runtime.h>
#include <hip/hip_bf16.h>

#define NS 2048
#define ND 64

typedef __attribute__((ext_vector_type(8))) short short8;
typedef __attribute__((ext_vector_type(4))) short short4v;
typedef __attribute__((ext_vector_type(4))) float f32x4;

static __device__ __forceinline__ short f2bf(float f) {
    union { __hip_bfloat16 h; short s; } u;
    u.h = __float2bfloat16(f);
    return u.s;
}
static __device__ __forceinline__ unsigned int pack2(float lo, float hi) {
    return (unsigned int)(unsigned short)f2bf(lo) |
           ((unsigned int)(unsigned short)f2bf(hi) << 16);
}
static __device__ __forceinline__ float exp2_fast(float x) {
    float r;
    asm("v_exp_f32 %0, %1" : "=v"(r) : "v"(x));
    return r;
}
static __device__ __forceinline__ unsigned int cvt_pk_bf16(float lo, float hi) {
    unsigned int w;
    asm("v_cvt_pk_bf16_f32 %0, %1, %2" : "=v"(w) : "v"(lo), "v"(hi));
    return w;
}

// ---------------- detect mask element stride (fallback path only) ----------
__global__ void detect_mask_kernel(const unsigned char* __restrict__ mask,
                                   int* __restrict__ flag) {
    const int i = threadIdx.x;  // 64 threads x 64 bytes
    unsigned int acc = 0;
    const uchar4* p = (const uchar4*)(mask + i * 64);
    #pragma unroll
    for (int j = 0; j < 16; ++j) {
        uchar4 v = p[j];
        acc |= (unsigned int)v.y | v.z | v.w;  // bytes at (off%4)!=0
    }
    const unsigned long long any = __ballot(acc != 0);
    if (i == 0) *flag = (any == 0ULL) ? 4 : 1;
}

// ---------------- pre-pass: K/V tile images + mask bit-words ---------------
// (round-11/12 proven image formats; round-13 proven inline mask detect)
// IMG per (bh,t): 8KB = [K 4x1KB | V 4x1KB]; 16B slot at chunk*1024 + lane*16
// holds that lane's full MFMA A-fragment (short8).
// Mask bits (causal pre-folded): word[((b*64+(q>>5))*64+t)*32+(q&31)] bit j =
//  mask[b][q][32t+j] && (32t+j <= q)
__global__ void prep_all(const float* __restrict__ K,
                         const float* __restrict__ V,
                         const unsigned char* __restrict__ M,
                         unsigned char* __restrict__ IMG,
                         unsigned int* __restrict__ Mbits) {
    if (blockIdx.x < 2048) {
        const int bid = blockIdx.x;          // (bh, T)
        const int bh = bid >> 6, T = bid & 63;
        const int i = threadIdx.x;
        __shared__ __align__(16) unsigned char img[8192];

        const int row = i >> 3;              // 0..31
        const int d0  = (i & 7) * 8;

        // ---- K ----
        {
            const float* src = K + ((size_t)(bh * NS + T * 32 + row)) * ND + d0;
            float4 f0 = ((const float4*)src)[0];
            float4 f1 = ((const float4*)src)[1];
            const float f[8] = {f0.x, f0.y, f0.z, f0.w, f1.x, f1.y, f1.z, f1.w};
            const int n = row >> 4, cc = row & 15;
            #pragma unroll
            for (int jp = 0; jp < 4; ++jp) {
                const int d  = d0 + 2 * jp;
                const int ch = d >> 5, dd = d & 31;
                const int g  = (dd & 15) >> 2;
                const int jj = (dd >> 4) * 2 + ((dd >> 1) & 1);
                *(unsigned int*)(img + (n * 2 + ch) * 1024 + (g * 16 + cc) * 16 + jj * 4) =
                    pack2(f[2 * jp], f[2 * jp + 1]);
            }
        }
        // ---- V ----
        {
            const int kv = row;
            const float* src = V + ((size_t)(bh * NS + T * 32 + kv)) * ND + d0;
            float4 f0 = ((const float4*)src)[0];
            float4 f1 = ((const float4*)src)[1];
            const float f[8] = {f0.x, f0.y, f0.z, f0.w, f1.x, f1.y, f1.z, f1.w};
            const int kl  = kv & ~1;
            const int q15 = kl & 15;
            const int g   = q15 >> 2;
            const int jj  = (kl >> 4) * 2 + ((q15 >> 1) & 1);
            const int half = (kv & 1) * 2;
            #pragma unroll
            for (int e = 0; e < 8; ++e) {
                const int d  = d0 + e;
                const int n4 = d >> 4, cv = d & 15;
                *(short*)(img + 4096 + n4 * 1024 + (g * 16 + cv) * 16 + jj * 4 + half) =
                    f2bf(f[e]);
            }
        }
        __syncthreads();
        uint4* dst = (uint4*)(IMG + ((size_t)bid << 13));
        const uint4* srcl = (const uint4*)img;
        dst[i * 2]     = srcl[i * 2];
        dst[i * 2 + 1] = srcl[i * 2 + 1];
    } else {
        // ---- inline mask-stride detection (first 4096 bytes of M) ----
        __shared__ int msh;
        {
            unsigned int accv = 0;
            if (threadIdx.x < 64) {
                const uint4* p4 = (const uint4*)(M + threadIdx.x * 64);
                #pragma unroll
                for (int jj = 0; jj < 4; ++jj) {
                    uint4 v = p4[jj];
                    accv |= (v.x & 0xFFFFFF00u) | (v.y & 0xFFFFFF00u) |
                            (v.z & 0xFFFFFF00u) | (v.w & 0xFFFFFF00u);
                }
            }
            const unsigned long long any = __ballot(accv != 0);
            if (threadIdx.x == 0) msh = (any == 0ULL) ? 4 : 1;
        }
        __syncthreads();
        const int ms = msh;

        const int id3 = (blockIdx.x - 2048) * 256 + threadIdx.x;   // 262144
        const int tt = id3 & 63, q = (id3 >> 6) & 2047, b = id3 >> 17;
        unsigned int w = 0;
        if (ms == 1) {
            const uint4* p = (const uint4*)(M + ((size_t)(b * NS + q)) * NS + tt * 32);
            uint4 A = p[0], B = p[1];
            const unsigned int u[8] = {A.x, A.y, A.z, A.w, B.x, B.y, B.z, B.w};
            #pragma unroll
            for (int i = 0; i < 8; ++i) {
                const unsigned int nib = (((u[i] & 0x01010101u) * 0x01020408u) >> 24) & 0xFu;
                w |= nib << (4 * i);
            }
        } else {
            const uint4* p = (const uint4*)(M + (((size_t)(b * NS + q)) * NS) * 4 + tt * 128);
            #pragma unroll
            for (int i = 0; i < 8; ++i) {
                uint4 A = p[i];
                w |= ((A.x & 1u) << (4 * i)) | ((A.y & 1u) << (4 * i + 1)) |
                     ((A.z & 1u) << (4 * i + 2)) | ((A.w & 1u) << (4 * i + 3));
            }
        }
        // causal fold: clear bits with kv = 32*tt + j > q
        const int qrel = q - 32 * tt;
        if (qrel < 0) w = 0;
        else if (qrel < 31) w &= ((2u << qrel) - 1u);
        Mbits[((size_t)(b * 64 + (q >> 5)) * 64 + tt) * 32 + (q & 31)] = w;
    }
}

// ---------------- main attention kernel ----------------
// Round-12 structure (PROVEN BEST): parity split — wave (p = wid&1,
// s = wid>>1) owns 32 q rows and kv tiles t == p (mod 2), t <= 2qi+s.
// LDS double-buffered pair staging (4 GLD/wave), one barrier per 64 kv.
// Fixed-base softmax, ones-row MFMA l-sum, additive parity merge.
// New this round: s_setprio(1) around the compute region (independent
// blocks per CU => role diversity, m191-style).
#define GLD(gsrc, ldst) __builtin_amdgcn_global_load_lds( \
    (const __attribute__((address_space(1))) unsigned int*)(gsrc), \
    (__attribute__((address_space(3))) unsigned int*)(ldst), 16, 0, 0)

__launch_bounds__(256, 4)
__global__ void attn_main(const float* __restrict__ Q,
                          const unsigned char* __restrict__ IMG,
                          const unsigned int* __restrict__ Mbits,
                          float* __restrict__ O) {
    const int idx = blockIdx.x;
    const int j   = (idx & 511) >> 5;
    const int bh  = idx & 31;
    const int qi  = (idx < 512) ? (31 - j) : j;   // 64-row q-tile, CU-balanced
    const int b   = bh >> 4;

    const int tid  = threadIdx.x;
    const int wid  = tid >> 6;
    const int lane = tid & 63;
    const int g = lane >> 4;
    const int c = lane & 15;
    const int p = wid & 1;     // kv-tile parity this wave computes
    const int s = wid >> 1;    // q 32-row subset

    const int q0w = qi * 64 + s * 32;

    const size_t bhoff = (size_t)bh * NS * ND;
    const float* Qb = Q + bhoff;
    float*       Ob = O + bhoff;
    const unsigned char* Tb = IMG + ((size_t)bh << 19);   // 64 tiles * 8192
    const unsigned int*  Mw = Mbits + ((size_t)(b * 64 + 2 * qi + s) << 11);

    // [buf][ tile(2tp) 8K | tile(2tp+1) 8K ]  (each tile: K 4K | V 4K)
    __shared__ __align__(16) unsigned char smem[2][16384];

    // Q fragments (2 m-tiles) with 0.125*log2(e) folded in
    const float QS = 0.18033688f;
    short8 aq[2][2];
    #pragma unroll
    for (int m = 0; m < 2; ++m) {
        const float* qrow = Qb + (size_t)(q0w + m * 16 + c) * ND;
        #pragma unroll
        for (int ch = 0; ch < 2; ++ch) {
            float4 x0 = *reinterpret_cast<const float4*>(qrow + ch * 32 + g * 4);
            float4 x1 = *reinterpret_cast<const float4*>(qrow + ch * 32 + 16 + g * 4);
            short8 fr;
            fr[0]=f2bf(x0.x*QS); fr[1]=f2bf(x0.y*QS); fr[2]=f2bf(x0.z*QS); fr[3]=f2bf(x0.w*QS);
            fr[4]=f2bf(x1.x*QS); fr[5]=f2bf(x1.y*QS); fr[6]=f2bf(x1.z*QS); fr[7]=f2bf(x1.w*QS);
            aq[m][ch] = fr;
        }
    }

    // ones-row A fragment: row 0 = 1.0 (lanes with c==0), else 0
    const short ov = (c == 0) ? (short)0x3F80 : (short)0;
    short8 onesf;
    #pragma unroll
    for (int e = 0; e < 8; ++e) onesf[e] = ov;

    f32x4 acc[2][4];
    f32x4 acc_l[2];
    #pragma unroll
    for (int m = 0; m < 2; ++m) {
        acc_l[m] = (f32x4){0.f, 0.f, 0.f, 0.f};
        #pragma unroll
        for (int n4 = 0; n4 < 4; ++n4) acc[m][n4] = (f32x4){0.f, 0.f, 0.f, 0.f};
    }

    const int NP   = qi + 1;        // pair iterations
    const int tmax = 2 * qi + s;    // last tile whose rows this wave needs

#define STAGE(B, TP) do { \
    const unsigned char* gp_ = Tb + ((size_t)(2 * (TP)) << 13) + (wid << 10) + (lane << 4); \
    unsigned char* lb_ = &smem[B][wid << 10]; \
    GLD(gp_,         lb_); \
    GLD(gp_ +  4096, lb_ +  4096); \
    GLD(gp_ +  8192, lb_ +  8192); \
    GLD(gp_ + 12288, lb_ + 12288); \
} while (0)

    STAGE(0, 0);
    unsigned int mk0 = Mw[p * 32 + c];        // tile t=p, row-block m=0
    unsigned int mk1 = Mw[p * 32 + 16 + c];   // tile t=p, row-block m=1
    asm volatile("s_waitcnt vmcnt(0)" ::: "memory");
    __syncthreads();

    for (int tp = 0; tp < NP; ++tp) {
        const int cur = tp & 1;
        const int t = 2 * tp + p;
        const bool havenext = (tp + 1 < NP);
        unsigned int nk0 = 0, nk1 = 0;
        if (havenext) {
            // mask words first (ride under compute with the GLDs)
            nk0 = Mw[(t + 2) * 32 + c];
            nk1 = Mw[(t + 2) * 32 + 16 + c];
            STAGE(cur ^ 1, tp + 1);
        }

        if (t <= tmax) {
            const unsigned char* kb = smem[cur] + (p << 13);
            const unsigned char* vb = kb + 4096;

            // 8x ds_read_b128, per-lane-contiguous (2-way bank alias = free)
            short8 kf[4], av[4];
            #pragma unroll
            for (int k4 = 0; k4 < 4; ++k4)
                kf[k4] = *(const short8*)(kb + k4 * 1024 + (lane << 4));
            #pragma unroll
            for (int n4 = 0; n4 < 4; ++n4)
                av[n4] = *(const short8*)(vb + n4 * 1024 + (lane << 4));

            __builtin_amdgcn_s_setprio(1);
            #pragma unroll
            for (int m = 0; m < 2; ++m) {
                f32x4 s0 = (f32x4){0.f, 0.f, 0.f, 0.f};
                f32x4 s1 = (f32x4){0.f, 0.f, 0.f, 0.f};
                s0 = __builtin_amdgcn_mfma_f32_16x16x32_bf16(kf[0], aq[m][0], s0, 0, 0, 0);
                s0 = __builtin_amdgcn_mfma_f32_16x16x32_bf16(kf[1], aq[m][1], s0, 0, 0, 0);
                s1 = __builtin_amdgcn_mfma_f32_16x16x32_bf16(kf[2], aq[m][0], s1, 0, 0, 0);
                s1 = __builtin_amdgcn_mfma_f32_16x16x32_bf16(kf[3], aq[m][1], s1, 0, 0, 0);

                const unsigned int mk = m ? mk1 : mk0;

                // fixed-base softmax: P = exp2(s), masked pre-exp2.
                // Causal pre-folded into mk => no edge handling anywhere.
                float pv[8];
                #pragma unroll
                for (int r = 0; r < 4; ++r) {
                    const unsigned int b0 = (mk >> (4 * g + r)) & 1u;
                    const unsigned int b1 = (mk >> (16 + 4 * g + r)) & 1u;
                    pv[r]     = exp2_fast(b0 ? s0[r] : -INFINITY);   // exp2(-inf)=0
                    pv[4 + r] = exp2_fast(b1 ? s1[r] : -INFINITY);
                }
                union { unsigned int u[4]; short8 v; } pfu;
                pfu.u[0] = cvt_pk_bf16(pv[0], pv[1]);
                pfu.u[1] = cvt_pk_bf16(pv[2], pv[3]);
                pfu.u[2] = cvt_pk_bf16(pv[4], pv[5]);
                pfu.u[3] = cvt_pk_bf16(pv[6], pv[7]);
                const short8 pf = pfu.v;

                #pragma unroll
                for (int n4 = 0; n4 < 4; ++n4)
                    acc[m][n4] = __builtin_amdgcn_mfma_f32_16x16x32_bf16(av[n4], pf, acc[m][n4], 0, 0, 0);
                acc_l[m] = __builtin_amdgcn_mfma_f32_16x16x32_bf16(onesf, pf, acc_l[m], 0, 0, 0);
            }
            __builtin_amdgcn_s_setprio(0);
        }

        mk0 = nk0; mk1 = nk1;
        asm volatile("s_waitcnt vmcnt(0)" ::: "memory");
        __syncthreads();
    }

    // ---- merge parity partials (pure addition; fixed base) ----
    float* MB = (float*)smem;   // 20KB used of 32KB; all compute reads done
    __syncthreads();
    if (p == 1) {
        #pragma unroll
        for (int m = 0; m < 2; ++m) {
            #pragma unroll
            for (int n4 = 0; n4 < 4; ++n4)
                *(f32x4*)&MB[(((s * 2 + m) * 4 + n4) * 64 + lane) * 4] = acc[m][n4];
            *(f32x4*)&MB[4096 + ((s * 2 + m) * 64 + lane) * 4] = acc_l[m];
        }
    }
    __syncthreads();
    if (p == 0) {
        #pragma unroll
        for (int m = 0; m < 2; ++m) {
            #pragma unroll
            for (int n4 = 0; n4 < 4; ++n4) {
                f32x4 o = *(const f32x4*)&MB[(((s * 2 + m) * 4 + n4) * 64 + lane) * 4];
                acc[m][n4][0] += o[0]; acc[m][n4][1] += o[1];
                acc[m][n4][2] += o[2]; acc[m][n4][3] += o[3];
            }
            f32x4 ol = *(const f32x4*)&MB[4096 + ((s * 2 + m) * 64 + lane) * 4];
            acc_l[m][0] += ol[0];
        }
        #pragma unroll
        for (int m = 0; m < 2; ++m) {
            const int q = q0w + m * 16 + c;
            const float lsum = __shfl(acc_l[m][0], c);   // row sum at lane c, reg 0
            const float inv = (lsum > 0.f) ? (1.f / lsum) : 0.f;
            float* orow = Ob + (size_t)q * ND;
            #pragma unroll
            for (int n4 = 0; n4 < 4; ++n4) {
                float4 o;
                o.x = acc[m][n4][0] * inv;
                o.y = acc[m][n4][1] * inv;
                o.z = acc[m][n4][2] * inv;
                o.w = acc[m][n4][3] * inv;
                *(float4*)(orow + n4 * 16 + 4 * g) = o;
            }
        }
    }
#undef STAGE
}

// ---------------- fallback (round-2 kernel, no workspace images) -----------
__launch_bounds__(128, 2)
__global__ void attn_fwd_fb(const float* __restrict__ Q,
                            const float* __restrict__ K,
                            const float* __restrict__ V,
                            const unsigned char* __restrict__ M,
                            float* __restrict__ O,
                            const int* __restrict__ mstride_p) {
    const int ms  = *mstride_p;
    const int idx = blockIdx.x;
    const int qi  = 31 - (idx >> 5);
    const int bh  = idx & 31;
    const int b   = bh >> 4;

    const int tid  = threadIdx.x;
    const int wid  = tid >> 6;
    const int lane = tid & 63;
    const int g = lane >> 4;
    const int c = lane & 15;

    const int q0w = qi * 64 + wid * 32;

    const size_t bhoff = (size_t)bh * NS * ND;
    const float* Qb = Q + bhoff;
    const float* Kb = K + bhoff;
    const float* Vb = V + bhoff;
    float*       Ob = O + bhoff;
    const unsigned char* Mb = M + (size_t)b * NS * NS * (size_t)ms;

    __shared__ __align__(16) unsigned char smem[2][8192];

    short8 aq[2][2];
    #pragma unroll
    for (int m = 0; m < 2; ++m) {
        const float* qrow = Qb + (size_t)(q0w + m * 16 + c) * ND;
        #pragma unroll
        for (int ch = 0; ch < 2; ++ch) {
            float4 x0 = *reinterpret_cast<const float4*>(qrow + ch * 32 + g * 4);
            float4 x1 = *reinterpret_cast<const float4*>(qrow + ch * 32 + 16 + g * 4);
            short8 fr;
            fr[0]=f2bf(x0.x); fr[1]=f2bf(x0.y); fr[2]=f2bf(x0.z); fr[3]=f2bf(x0.w);
            fr[4]=f2bf(x1.x); fr[5]=f2bf(x1.y); fr[6]=f2bf(x1.z); fr[7]=f2bf(x1.w);
            aq[m][ch] = fr;
        }
    }

    f32x4 acc[2][4];
    float m_run[2], l_run[2];
    #pragma unroll
    for (int m = 0; m < 2; ++m) {
        m_run[m] = -INFINITY; l_run[m] = 0.f;
        #pragma unroll
        for (int n4 = 0; n4 < 4; ++n4) acc[m][n4] = (f32x4){0.f, 0.f, 0.f, 0.f};
    }

    const int NT = 2 * qi + 2;

    const int krow = tid >> 2;
    const int kcb  = (tid & 3) * 16;
    const int ksw  = (krow & 7) << 4;
    const int vkp  = tid >> 3;
    const int vdb  = tid & 7;
    const int vg   = (vkp >> 1) & 3;
    const int vep  = (vkp & 1) + 2 * (vkp >> 3);
    const float* kbase = Kb + (size_t)krow * ND + kcb;
    const float* vbase = Vb + (size_t)(2 * vkp) * ND + vdb * 8;

    float4 kin0, kin1, kin2, kin3, vin0, vin1, vin2, vin3;

#define STAGE_LOAD(T) do { \
    const float* kp_ = kbase + (size_t)(T) * 32 * ND; \
    kin0 = *(const float4*)(kp_);      kin1 = *(const float4*)(kp_ + 4); \
    kin2 = *(const float4*)(kp_ + 8);  kin3 = *(const float4*)(kp_ + 12); \
    const float* vp_ = vbase + (size_t)(T) * 32 * ND; \
    vin0 = *(const float4*)(vp_);      vin1 = *(const float4*)(vp_ + 4); \
    vin2 = *(const float4*)(vp_ + ND); vin3 = *(const float4*)(vp_ + ND + 4); \
} while (0)

#define STAGE_WRITE(BUF) do { \
    unsigned char* kb_ = smem[BUF]; \
    short8 w0, w1; \
    w0[0]=f2bf(kin0.x); w0[1]=f2bf(kin0.y); w0[2]=f2bf(kin0.z); w0[3]=f2bf(kin0.w); \
    w0[4]=f2bf(kin1.x); w0[5]=f2bf(kin1.y); w0[6]=f2bf(kin1.z); w0[7]=f2bf(kin1.w); \
    w1[0]=f2bf(kin2.x); w1[1]=f2bf(kin2.y); w1[2]=f2bf(kin2.z); w1[3]=f2bf(kin2.w); \
    w1[4]=f2bf(kin3.x); w1[5]=f2bf(kin3.y); w1[6]=f2bf(kin3.z); w1[7]=f2bf(kin3.w); \
    *(short8*)(kb_ + krow * 128 + ((kcb * 2) ^ ksw))      = w0; \
    *(short8*)(kb_ + krow * 128 + ((kcb * 2 + 16) ^ ksw)) = w1; \
    unsigned char* vb_ = smem[BUF] + 4096; \
    const float lo_[8] = {vin0.x, vin0.y, vin0.z, vin0.w, vin1.x, vin1.y, vin1.z, vin1.w}; \
    const float hi_[8] = {vin2.x, vin2.y, vin2.z, vin2.w, vin3.x, vin3.y, vin3.z, vin3.w}; \
    _Pragma("unroll") \
    for (int j_ = 0; j_ < 8; ++j_) { \
        const int d_ = vdb * 8 + j_; \
        const int n4_ = d_ >> 4; \
        const int cc_ = d_ & 15; \
        const int aw_ = ((n4_ * 4 + vep) * 64 + ((vg * 16 + cc_) ^ ((vep << 3) | n4_))) * 4; \
        *(unsigned int*)(vb_ + aw_) = pack2(lo_[j_], hi_[j_]); \
    } \
} while (0)

    STAGE_LOAD(0);
    STAGE_WRITE(0);
    __syncthreads();

    const float SC = 0.125f;

    for (int t = 0; t < NT; ++t) {
        const int cur = t & 1;
        const bool havenext = (t + 1 < NT);
        if (havenext) STAGE_LOAD(t + 1);

        const unsigned char* kb = smem[cur];
        const int sw = (c & 7) << 4;
        short8 kf[2][2];
        #pragma unroll
        for (int n = 0; n < 2; ++n) {
            const int row = n * 16 + c;
            #pragma unroll
            for (int ch = 0; ch < 2; ++ch) {
                short4v lo = *(const short4v*)(kb + row * 128 + ((ch * 64 + g * 8) ^ sw));
                short4v hi = *(const short4v*)(kb + row * 128 + ((ch * 64 + g * 8 + 32) ^ sw));
                short8 fr;
                fr[0]=lo[0]; fr[1]=lo[1]; fr[2]=lo[2]; fr[3]=lo[3];
                fr[4]=hi[0]; fr[5]=hi[1]; fr[6]=hi[2]; fr[7]=hi[3];
                kf[n][ch] = fr;
            }
        }
        const unsigned char* vbuf = smem[cur] + 4096;
        short8 av[4];
        #pragma unroll
        for (int n4 = 0; n4 < 4; ++n4) {
            short8 fr;
            #pragma unroll
            for (int ep = 0; ep < 4; ++ep) {
                unsigned int w = *(const unsigned int*)
                    (vbuf + (((n4 * 4 + ep) * 64 + (lane ^ ((ep << 3) | n4))) * 4));
                fr[2 * ep]     = (short)(w & 0xffff);
                fr[2 * ep + 1] = (short)(w >> 16);
            }
            av[n4] = fr;
        }

        const int kv0 = t * 32;
        #pragma unroll
        for (int m = 0; m < 2; ++m) {
            const int q = q0w + m * 16 + c;

            f32x4 s[2];
            #pragma unroll
            for (int n = 0; n < 2; ++n) {
                f32x4 z = {0.f, 0.f, 0.f, 0.f};
                z = __builtin_amdgcn_mfma_f32_16x16x32_bf16(kf[n][0], aq[m][0], z, 0, 0, 0);
                z = __builtin_amdgcn_mfma_f32_16x16x32_bf16(kf[n][1], aq[m][1], z, 0, 0, 0);
                s[n] = z;
            }

            unsigned int mk0, mk1;
            if (ms == 1) {
                mk0 = *(const unsigned int*)(Mb + (size_t)q * NS + kv0 + 4 * g);
                mk1 = *(const unsigned int*)(Mb + (size_t)q * NS + kv0 + 16 + 4 * g);
            } else {
                const uint4 a4 = *(const uint4*)(Mb + ((size_t)q * NS + kv0 + 4 * g) * 4);
                const uint4 b4 = *(const uint4*)(Mb + ((size_t)q * NS + kv0 + 16 + 4 * g) * 4);
                mk0 = (a4.x?1u:0u) | (a4.y?0x100u:0u) | (a4.z?0x10000u:0u) | (a4.w?0x1000000u:0u);
                mk1 = (b4.x?1u:0u) | (b4.y?0x100u:0u) | (b4.z?0x10000u:0u) | (b4.w?0x1000000u:0u);
            }

            float mx = -INFINITY;
            #pragma unroll
            for (int n = 0; n < 2; ++n) {
                const unsigned int mk = n ? mk1 : mk0;
                #pragma unroll
                for (int r = 0; r < 4; ++r) {
                    const int kv = kv0 + n * 16 + 4 * g + r;
                    const bool keep = (((mk >> (8 * r)) & 0xffu) != 0u) && (kv <= q);
                    const float val = keep ? s[n][r] * SC : -INFINITY;
                    s[n][r] = val;
                    mx = fmaxf(mx, val);
                }
            }
            mx = fmaxf(mx, __shfl_xor(mx, 16));
            mx = fmaxf(mx, __shfl_xor(mx, 32));

            const float m_new = fmaxf(m_run[m], mx);
            const float alpha = (m_run[m] == -INFINITY) ? 0.f : __expf(m_run[m] - m_new);
            m_run[m] = m_new;
            const float msafe = (m_new == -INFINITY) ? 0.f : m_new;

            float sum = 0.f;
            short8 pf;
            #pragma unroll
            for (int n = 0; n < 2; ++n)
                #pragma unroll
                for (int r = 0; r < 4; ++r) {
                    const float pvv = __expf(s[n][r] - msafe);
                    sum += pvv;
                    pf[n * 4 + r] = f2bf(pvv);
                }
            sum += __shfl_xor(sum, 16);
            sum += __shfl_xor(sum, 32);
            l_run[m] = l_run[m] * alpha + sum;

            #pragma unroll
            for (int n4 = 0; n4 < 4; ++n4) {
                f32x4 o = acc[m][n4];
                o[0] *= alpha; o[1] *= alpha; o[2] *= alpha; o[3] *= alpha;
                o = __builtin_amdgcn_mfma_f32_16x16x32_bf16(av[n4], pf, o, 0, 0, 0);
                acc[m][n4] = o;
            }
        }

        if (havenext) STAGE_WRITE(cur ^ 1);
        __syncthreads();
    }

    #pragma unroll
    for (int m = 0; m < 2; ++m) {
        const int q = q0w + m * 16 + c;
        const float inv = (l_run[m] > 0.f) ? (1.f / l_run[m]) : 0.f;
        float* orow = Ob + (size_t)q * ND;
        #pragma unroll
        for (int n4 = 0; n4 < 4; ++n4) {
            float4 o;
            o.x = acc[m][n4][0] * inv;
            o.y = acc[m][n4][1] * inv;
            o.z = acc[m][n4][2] * inv;
            o.w = acc[m][n4][3] * inv;
            *(float4*)(orow + n4 * 16 + 4 * g) = o;
        }
    }
#undef STAGE_LOAD
#undef STAGE_WRITE
}

extern "C" void kernel_launch(void* const* d_in, const int* in_sizes, int n_in,
                              void* d_out, int out_size, void* d_ws, size_t ws_size,
                              hipStream_t stream) {
    const float* Q = (const float*)d_in[0];
    const float* K = (const float*)d_in[1];
    const float* V = (const float*)d_in[2];
    const unsigned char* M = (const unsigned char*)d_in[3];
    float* O = (float*)d_out;

    unsigned char* ws = (unsigned char*)d_ws;
    const size_t IMG_SZ  = (size_t)2048 * 8192;              // 16 MB
    const size_t BITS_SZ = (size_t)2 * 64 * 64 * 32 * 4;     // 2 MB
    const size_t NEED = 1024 + IMG_SZ + BITS_SZ;

    if (ws_size >= NEED) {
        unsigned char* IMG  = ws + 1024;
        unsigned int* Mbits = (unsigned int*)(ws + 1024 + IMG_SZ);
        hipLaunchKernelGGL(prep_all, dim3(3072), dim3(256), 0, stream,
                           K, V, M, IMG, Mbits);
        hipLaunchKernelGGL(attn_main, dim3(1024), dim3(256), 0, stream,
                           Q, IMG, Mbits, O);
    } else {
        int* flag = (int*)ws;
        hipLaunchKernelGGL(detect_mask_kernel, dim3(1), dim3(64), 0, stream, M, flag);
        hipLaunchKernelGGL(attn_fwd_fb, dim3(1024), dim3(128), 0, stream,
                           Q, K, V, M, O, flag);
    }
}